// Round 2
// baseline (333.245 us; speedup 1.0000x reference)
//
#include <hip/hip_runtime.h>
#include <hip/hip_bf16.h>

// Pipeline: roi_align -> conv3x3(C=256->E=256 on 3x3 spatial, pad 1) -> GroupNorm(8)
//           -> ReLU -> spatial mean -> head GEMM -> +spat +sym_emb -> per-sid fuse matvec.
// Sizes: B=2, C=E=256, S=3, L=5, N=128, HMAX=128.
// R13: kill the pathological ROI gather. Old gather lane-dim was c with 64 KB
// stride -> 64 lines + 64 pages per wave-load, 8x line over-fetch. New: prep
// transposes the VALID fm regions (44.7 MB of the padded 167 MB) to
// fmT[l][b][y][x][c] (c innermost). Bilinear corner reads become contiguous
// 1 KB/lane-row loads. Gather moves into the conv kernel (sample-local -> LDS),
// roiT roundtrip and its 1152 prep blocks deleted.
// R12: conv+GN+head fused per-sample (block = n, 512 thr), (e, e+128) v_pk_fma.
// R10: k-paired bf16 head/fuse weights. R5: no device fences. R3: transposed matvec.

typedef float v2f __attribute__((ext_vector_type(2)));

__device__ __forceinline__ float bf_lo(unsigned u) { return __uint_as_float(u << 16); }
__device__ __forceinline__ float bf_hi(unsigned u) { return __uint_as_float(u & 0xffff0000u); }
__device__ __forceinline__ unsigned short f2bf(float f) {
    __hip_bfloat16 h = __float2bfloat16(f);
    return *(unsigned short*)&h;
}

// fmT vector offsets per level (units of 256-float c-vectors):
// l0:0  l1:2*128^2=32768  l2:+2*64^2=40960  l3:+2*32^2=43008  l4:+2*16^2=43520, end 43648
__constant__ int VOFF_c[5] = {0, 32768, 40960, 43008, 43520};

// ---------------- fused prep kernel ----------------
// grid.x: [0,256)     w_prep (block=c, thread=e)
//         [256,704)   t7     (448 tiles: head_w + 6x fuse_w -> transposed k-paired bf16)
//         [704,1200)  fm transpose: block = (l,b,y) row; fm[l][b][c][y][x] -> fmT[...][x][c]
__global__ __launch_bounds__(256) void prep_k(
    const float* __restrict__ conv_w,
    const float* __restrict__ head_w, const float* __restrict__ fuse_w,
    const float* __restrict__ fm,
    unsigned short* __restrict__ w8, unsigned short* __restrict__ w9,
    unsigned short* __restrict__ head_wTb, unsigned short* __restrict__ fuse_wTb,
    float* __restrict__ fmT) {
    int blk = blockIdx.x;
    int t = threadIdx.x;

    if (blk < 256) {
        // conv weight repack: [e][c][9] f32 -> w8[c][e][8] + w9[c][e] bf16
        int c = blk, e = t;
        const float* src = conv_w + ((size_t)e * 256 + c) * 9;
        unsigned short tmp[8];
#pragma unroll
        for (int k = 0; k < 8; ++k) tmp[k] = f2bf(src[k]);
        ((uint4*)w8)[(size_t)c * 256 + e] = *(const uint4*)tmp;
        w9[(size_t)c * 256 + e] = f2bf(src[8]);
        return;
    }

    if (blk < 704) {
        // 32x32 tiled transpose of head_w (z=0) / fuse_w (z=1..6).
        // Output: k-paired bf16 — ushort index ((k>>1)*256 + e)*2 + (k&1).
        __shared__ float tile[32][33];
        int q = blk - 256;
        int z = q >> 6;
        int rem = q & 63;
        int bx = (rem & 7) * 32, by = (rem >> 3) * 32;
        const float* in = (z == 0) ? head_w : fuse_w + (size_t)(z - 1) * 65536;
        unsigned short* out = (z == 0) ? head_wTb : fuse_wTb + (size_t)(z - 1) * 65536;
        int tx = t & 31, ty = t >> 5;
#pragma unroll
        for (int i = 0; i < 32; i += 8)
            tile[ty + i][tx] = in[(size_t)(by + ty + i) * 256 + bx + tx];
        __syncthreads();
#pragma unroll
        for (int i = 0; i < 32; i += 8) {
            int k = bx + ty + i;          // transposed row (original col)
            int e = by + tx;
            out[(size_t)((k >> 1) * 256 + e) * 2 + (k & 1)] = f2bf(tile[tx][ty + i]);
        }
        return;
    }

    // fm transpose. 496 row-blocks: l0 has 2*128, l1 2*64, l2 2*32, l3 2*16, l4 2*8.
    {
        __shared__ float tile[64][129];   // +1 pad: write phase reads column-wise
        int r = blk - 704;
        int l, base;
        if      (r < 256) { l = 0; base = 0;   }
        else if (r < 384) { l = 1; base = 256; }
        else if (r < 448) { l = 2; base = 384; }
        else if (r < 480) { l = 3; base = 448; }
        else              { l = 4; base = 480; }
        int szi = 128 >> l;
        int local = r - base;
        int b = (local >= szi) ? 1 : 0;
        int y = local - b * szi;

        size_t src_row = ((size_t)(l * 2 + b) * 256) * 16384 + (size_t)y * 128;
        size_t dst_vec0 = (size_t)VOFF_c[l] + (size_t)b * szi * szi + (size_t)y * szi;

        int lane = t & 63, cq = t >> 6;   // 4 c-rows per read iteration
        for (int c0 = 0; c0 < 256; c0 += 64) {
#pragma unroll
            for (int i = 0; i < 16; ++i) {
                int cl = cq * 16 + i;
                size_t sa = src_row + (size_t)(c0 + cl) * 16384;
                if (lane < szi) tile[cl][lane] = fm[sa + lane];
                if (szi == 128) tile[cl][lane + 64] = fm[sa + lane + 64];
            }
            __syncthreads();
            int cc = t & 63, xq = t >> 6;
            for (int x = xq; x < szi; x += 4)
                fmT[(dst_vec0 + x) * 256 + c0 + cc] = tile[cc][x];
            __syncthreads();
        }
    }
}

// ---------------- roi gather + conv3x3 + GN + ReLU + mean + head + fuse ----------------
// Block = n (128 blocks x 512 threads).
// Phase 0: coalesced bilinear gather from fmT -> roi_lds[9][256] (lane = c).
// Conv: ep = t&127 (lane owns e=ep AND e=ep+128 in v2f), ch = t>>7 (4 c-slices).
// roi values wave-uniform ds reads; weight pair (e, e+128) two coalesced uint4 loads.
__global__ __launch_bounds__(512, 2) void conv_gn_head(
    const float* __restrict__ fmT, const float* __restrict__ boxes,
    const int* __restrict__ batch_idx, const int* __restrict__ level_idx,
    const unsigned short* __restrict__ w8, const unsigned short* __restrict__ w9,
    const float* __restrict__ gn_scale, const float* __restrict__ gn_bias,
    const unsigned short* __restrict__ head_wTb, const float* __restrict__ head_b,
    const float* __restrict__ spat_w, const float* __restrict__ spat_b,
    const float* __restrict__ sym_emb,
    const unsigned short* __restrict__ fuse_wTb, const float* __restrict__ fuse_b,
    const int* __restrict__ sym_ids, float* __restrict__ out) {
    __shared__ float roi_lds[9 * 256];    // 9216 B
    __shared__ v2f red[2 * 128 * 9];      // 18432 B c-slice reduction
    __shared__ float pl[256];             // pooled
    __shared__ float part[512];
    __shared__ float fin[256];

    int n = blockIdx.x;
    int t = threadIdx.x;

    // ---- phase 0: ROI gather (coalesced: lane = c) ----
    {
        int c = t & 255;
        int ph = t >> 8;                  // 0 -> p 0..4, 1 -> p 5..8
        int lvl = level_idx[n];
        int b = batch_idx[n];
        const float sizes[5]  = {128.f, 64.f, 32.f, 16.f, 8.f};
        const float invstr[5] = {1.f/8.f, 1.f/16.f, 1.f/32.f, 1.f/64.f, 1.f/128.f};
        float scale = invstr[lvl];
        float hv = sizes[lvl];
        int szi = 128 >> lvl;
        size_t base_vec = (size_t)VOFF_c[lvl] + (size_t)b * szi * szi;

        float bx1 = boxes[n*4+0] * scale, by1 = boxes[n*4+1] * scale;
        float bx2 = boxes[n*4+2] * scale, by2 = boxes[n*4+3] * scale;
        float rw = fmaxf(bx2 - bx1, 1.f), rh = fmaxf(by2 - by1, 1.f);

        int pend = ph ? 9 : 5;
        for (int p = ph * 5; p < pend; ++p) {
            int i = p / 3, j = p % 3;
            float x = bx1 + (((float)j + 0.5f) / 3.f) * rw;
            float y = by1 + (((float)i + 0.5f) / 3.f) * rh;
            bool valid = (y > -1.f) && (y < hv) && (x > -1.f) && (x < hv);
            float yc = fminf(fmaxf(y, 0.f), hv - 1.f);
            float xc = fminf(fmaxf(x, 0.f), hv - 1.f);
            int y0 = (int)floorf(yc), x0 = (int)floorf(xc);
            int hi = szi - 1;
            int y1i = min(y0 + 1, hi), x1i = min(x0 + 1, hi);
            float ly = yc - (float)y0, lx = xc - (float)x0;

            float v00 = fmT[(base_vec + y0  * szi + x0 ) * 256 + c];
            float v01 = fmT[(base_vec + y0  * szi + x1i) * 256 + c];
            float v10 = fmT[(base_vec + y1i * szi + x0 ) * 256 + c];
            float v11 = fmT[(base_vec + y1i * szi + x1i) * 256 + c];
            float v = (1.f - ly) * (1.f - lx) * v00 + (1.f - ly) * lx * v01 +
                      ly * (1.f - lx) * v10 + ly * lx * v11;
            roi_lds[p * 256 + c] = valid ? v : 0.f;
        }
    }
    __syncthreads();

    // ---- conv ----
    int ep = t & 127;
    int ch = __builtin_amdgcn_readfirstlane(t >> 7);   // wave-uniform 0..3

    v2f acc[9];
#pragma unroll
    for (int p = 0; p < 9; ++p) acc[p] = (v2f)(0.f);

    int c0 = ch * 64;
#pragma unroll 2
    for (int c = c0; c < c0 + 64; c += 2) {
        // wave-uniform float2 roi reads from LDS (broadcast)
        v2f q[9];
#pragma unroll
        for (int jj = 0; jj < 9; ++jj)
            q[jj] = *(const v2f*)(&roi_lds[jj * 256 + c]);

#pragma unroll
        for (int cc = 0; cc < 2; ++cc) {
            int cw = c + cc;
            uint4 wa = ((const uint4*)w8)[(size_t)cw * 256 + ep];         // taps e=ep
            uint4 wb = ((const uint4*)w8)[(size_t)cw * 256 + ep + 128];   // taps e=ep+128
            v2f w2[9];
            w2[0].x = bf_lo(wa.x); w2[0].y = bf_lo(wb.x);
            w2[1].x = bf_hi(wa.x); w2[1].y = bf_hi(wb.x);
            w2[2].x = bf_lo(wa.y); w2[2].y = bf_lo(wb.y);
            w2[3].x = bf_hi(wa.y); w2[3].y = bf_hi(wb.y);
            w2[4].x = bf_lo(wa.z); w2[4].y = bf_lo(wb.z);
            w2[5].x = bf_hi(wa.z); w2[5].y = bf_hi(wb.z);
            w2[6].x = bf_lo(wa.w); w2[6].y = bf_lo(wb.w);
            w2[7].x = bf_hi(wa.w); w2[7].y = bf_hi(wb.w);
            w2[8].x = bf_lo((unsigned)w9[(size_t)cw * 256 + ep]);
            w2[8].y = bf_lo((unsigned)w9[(size_t)cw * 256 + ep + 128]);

            v2f rr[9];                      // splat wave-uniform roi value
#pragma unroll
            for (int jj = 0; jj < 9; ++jj) {
                float rv = cc ? q[jj].y : q[jj].x;
                rr[jj].x = rv; rr[jj].y = rv;
            }
#pragma unroll
            for (int ky = 0; ky < 3; ++ky) {
#pragma unroll
                for (int kx = 0; kx < 3; ++kx) {
                    v2f wk = w2[ky * 3 + kx];
#pragma unroll
                    for (int oy = 0; oy < 3; ++oy) {
                        int iy = oy + ky - 1;
                        if (iy < 0 || iy > 2) continue;
#pragma unroll
                        for (int ox = 0; ox < 3; ++ox) {
                            int ix = ox + kx - 1;
                            if (ix < 0 || ix > 2) continue;
                            int o = oy * 3 + ox, in = iy * 3 + ix;
                            acc[o] = wk * rr[in] + acc[o];   // -> v_pk_fma_f32
                        }
                    }
                }
            }
        }
    }

    // tree-reduce 4 c-slices into ch==0
    if (ch >= 2) {
#pragma unroll
        for (int p = 0; p < 9; ++p)
            red[((ch - 2) * 128 + ep) * 9 + p] = acc[p];
    }
    __syncthreads();
    if (ch < 2) {
#pragma unroll
        for (int p = 0; p < 9; ++p)
            acc[p] += red[(ch * 128 + ep) * 9 + p];
    }
    __syncthreads();
    if (ch == 1) {
#pragma unroll
        for (int p = 0; p < 9; ++p)
            red[ep * 9 + p] = acc[p];
    }
    __syncthreads();

    if (ch == 0) {
#pragma unroll
        for (int p = 0; p < 9; ++p)
            acc[p] += red[ep * 9 + p];

        // GroupNorm: group = e>>5. 32-lane halves share the group for BOTH v2f
        // components (g = ep>>5 for .x, g+4 for .y).
        v2f s = (v2f)(0.f), sq = (v2f)(0.f);
#pragma unroll
        for (int p = 0; p < 9; ++p) { s += acc[p]; sq += acc[p] * acc[p]; }
#pragma unroll
        for (int m = 16; m >= 1; m >>= 1) {
            s.x  += __shfl_xor(s.x,  m, 64);
            s.y  += __shfl_xor(s.y,  m, 64);
            sq.x += __shfl_xor(sq.x, m, 64);
            sq.y += __shfl_xor(sq.y, m, 64);
        }
        float mean0 = s.x * (1.f / 288.f), mean1 = s.y * (1.f / 288.f);
        float var0 = sq.x * (1.f / 288.f) - mean0 * mean0;
        float var1 = sq.y * (1.f / 288.f) - mean1 * mean1;
        float ri0 = rsqrtf(var0 + 1e-5f), ri1 = rsqrtf(var1 + 1e-5f);
        float gs0 = gn_scale[ep],       gb0 = gn_bias[ep];
        float gs1 = gn_scale[ep + 128], gb1 = gn_bias[ep + 128];
        float ps0 = 0.f, ps1 = 0.f;
#pragma unroll
        for (int p = 0; p < 9; ++p) {
            float v0 = (acc[p].x - mean0) * ri0 * gs0 + gb0;
            float v1 = (acc[p].y - mean1) * ri1 * gs1 + gb1;
            ps0 += fmaxf(v0, 0.f);
            ps1 += fmaxf(v1, 0.f);
        }
        pl[ep]       = ps0 * (1.f / 9.f);
        pl[ep + 128] = ps1 * (1.f / 9.f);
    }
    __syncthreads();

    // ---- head GEMM + spat + sym_emb + fuse matvec (k-split x2) ----
    int e = t & 255;
    int kh = t >> 8;                      // 0/1
    int sid = sym_ids[n];

    {
        float a2 = 0.f;
        const unsigned* w = (const unsigned*)head_wTb + (size_t)(kh * 64) * 256 + e;
        const float* p = pl + kh * 128;
#pragma unroll 8
        for (int kp = 0; kp < 64; ++kp) {
            unsigned u = w[kp * 256];
            a2 = fmaf(p[2 * kp],     bf_lo(u), a2);
            a2 = fmaf(p[2 * kp + 1], bf_hi(u), a2);
        }
        part[t] = a2;
    }
    __syncthreads();
    if (t < 256) {
        float ho = fmaxf(part[t] + part[t + 256] + head_b[t], 0.f);
        float4 sw = ((const float4*)spat_w)[t];
        float b0 = boxes[n*4+0], b1 = boxes[n*4+1], b2 = boxes[n*4+2], b3 = boxes[n*4+3];
        float sp = fmaxf(spat_b[t] + b0*sw.x + b1*sw.y + b2*sw.z + b3*sw.w, 0.f);
        fin[t] = ho + sp + sym_emb[sid * 256 + t];
    }
    __syncthreads();
    {
        float o = 0.f;
        const unsigned* w = (const unsigned*)fuse_wTb + (size_t)sid * 32768
                            + (size_t)(kh * 64) * 256 + e;
        const float* p = fin + kh * 128;
#pragma unroll 8
        for (int kp = 0; kp < 64; ++kp) {
            unsigned u = w[kp * 256];
            o = fmaf(p[2 * kp],     bf_lo(u), o);
            o = fmaf(p[2 * kp + 1], bf_hi(u), o);
        }
        part[t] = o;
    }
    __syncthreads();
    if (t < 256)
        out[(size_t)n * 256 + t] = fmaxf(part[t] + part[t + 256] + fuse_b[sid * 256 + t], 0.f);
}

extern "C" void kernel_launch(void* const* d_in, const int* in_sizes, int n_in,
                              void* d_out, int out_size, void* d_ws, size_t ws_size,
                              hipStream_t stream) {
    const float* fm      = (const float*)d_in[0];
    const float* boxes   = (const float*)d_in[1];
    const float* conv_w  = (const float*)d_in[2];
    const float* gn_s    = (const float*)d_in[3];
    const float* gn_b    = (const float*)d_in[4];
    const float* head_w  = (const float*)d_in[5];
    const float* head_b  = (const float*)d_in[6];
    const float* spat_w  = (const float*)d_in[7];
    const float* spat_b  = (const float*)d_in[8];
    const float* sym_emb = (const float*)d_in[9];
    const float* fuse_w  = (const float*)d_in[10];
    const float* fuse_b  = (const float*)d_in[11];
    const int* batch_idx = (const int*)d_in[12];
    const int* level_idx = (const int*)d_in[13];
    const int* sym_ids   = (const int*)d_in[14];
    float* outp = (float*)d_out;

    char* ws = (char*)d_ws;
    unsigned short* w8       = (unsigned short*)ws;             // [256c][256e][8] bf16: 1,048,576 B
    unsigned short* w9       = (unsigned short*)(ws + 1048576); // [256c][256e] bf16  :   131,072 B
    unsigned short* head_wTb = (unsigned short*)(ws + 1179648); // [128kp][256e][2]   :   131,072 B
    unsigned short* fuse_wTb = (unsigned short*)(ws + 1310720); // [6][128kp][256e][2]:   786,432 B
    float* fmT     = (float*)(ws + 2097152);                    // 43648 vecs x 1 KB  : 44,695,552 B

    prep_k<<<1200, 256, 0, stream>>>(conv_w, head_w, fuse_w, fm,
                                     w8, w9, head_wTb, fuse_wTb, fmT);
    conv_gn_head<<<128, 512, 0, stream>>>(fmT, boxes, batch_idx, level_idx,
                                          w8, w9, gn_s, gn_b,
                                          head_wTb, head_b, spat_w, spat_b,
                                          sym_emb, fuse_wTb, fuse_b, sym_ids, outp);
}

// Round 3
// 250.998 us; speedup vs baseline: 1.3277x; 1.3277x over previous
//
#include <hip/hip_runtime.h>
#include <hip/hip_bf16.h>

// Pipeline: roi_align -> conv3x3(C=256->E=256 on 3x3 spatial, pad 1) -> GroupNorm(8)
//           -> ReLU -> spatial mean -> head GEMM -> +spat +sym_emb -> per-sid fuse matvec.
// Sizes: B=2, C=E=256, S=3, L=5, N=128, HMAX=128.
// R14: revert to R11 structure (3 launches, best 249.98). ONE change: roi gather
// loop-nest reorder. Old: block=(n,p), lane=c -> 64 KB lane stride = 64 lines +
// 64 PAGES per wave-load, UTCL1 thrash, walker-serialized. New: block=c,
// lanes=(n,p): a wave's 64 lanes read within the ~10 planes of ONE c (~45 pages
// per block, reused over all 4608 loads). Blocks have disjoint fm footprints.
// roiT layout/math identical; writes scattered but posted (1.2 MB total).
// R13 lesson: full fm transpose costs more than the gather (fills flush L3 every
// iter -> 90 MB cold traffic). R12 lesson: conv at 128 blocks loses more than a
// launch saves. R10: c-paired roi loads + k-paired bf16 weights. R3: transposed.

typedef float v2f __attribute__((ext_vector_type(2)));

__device__ __forceinline__ float bf_lo(unsigned u) { return __uint_as_float(u << 16); }
__device__ __forceinline__ float bf_hi(unsigned u) { return __uint_as_float(u & 0xffff0000u); }
__device__ __forceinline__ unsigned short f2bf(float f) {
    __hip_bfloat16 h = __float2bfloat16(f);
    return *(unsigned short*)&h;
}

// ---------------- fused prep kernel ----------------
// grid.x: [0,256)    w_prep (block=c, thread=e)
//         [256,704)  t7     (448 tiles: head_w + 6x fuse_w -> transposed k-paired bf16)
//         [704,960)  roi    (block = c, lanes = (n,p): wave = 64 consecutive n, fixed p parity)
__global__ __launch_bounds__(256) void prep_k(
    const float* __restrict__ conv_w,
    const float* __restrict__ head_w, const float* __restrict__ fuse_w,
    const float* __restrict__ fm, const float* __restrict__ boxes,
    const int* __restrict__ batch_idx, const int* __restrict__ level_idx,
    unsigned short* __restrict__ w8, unsigned short* __restrict__ w9,
    unsigned short* __restrict__ head_wTb, unsigned short* __restrict__ fuse_wTb,
    float* __restrict__ roiT) {
    int blk = blockIdx.x;
    int t = threadIdx.x;

    if (blk < 256) {
        // conv weight repack: [e][c][9] f32 -> w8[c][e][8] + w9[c][e] bf16
        int c = blk, e = t;
        const float* src = conv_w + ((size_t)e * 256 + c) * 9;
        unsigned short tmp[8];
#pragma unroll
        for (int k = 0; k < 8; ++k) tmp[k] = f2bf(src[k]);
        ((uint4*)w8)[(size_t)c * 256 + e] = *(const uint4*)tmp;
        w9[(size_t)c * 256 + e] = f2bf(src[8]);
        return;
    }

    if (blk < 704) {
        // 32x32 tiled transpose of head_w (z=0) / fuse_w (z=1..6).
        // Output: k-paired bf16 — ushort index ((k>>1)*256 + e)*2 + (k&1).
        __shared__ float tile[32][33];
        int q = blk - 256;
        int z = q >> 6;
        int rem = q & 63;
        int bx = (rem & 7) * 32, by = (rem >> 3) * 32;
        const float* in = (z == 0) ? head_w : fuse_w + (size_t)(z - 1) * 65536;
        unsigned short* out = (z == 0) ? head_wTb : fuse_wTb + (size_t)(z - 1) * 65536;
        int tx = t & 31, ty = t >> 5;
#pragma unroll
        for (int i = 0; i < 32; i += 8)
            tile[ty + i][tx] = in[(size_t)(by + ty + i) * 256 + bx + tx];
        __syncthreads();
#pragma unroll
        for (int i = 0; i < 32; i += 8) {
            int k = bx + ty + i;          // transposed row (original col)
            int e = by + tx;
            out[(size_t)((k >> 1) * 256 + e) * 2 + (k & 1)] = f2bf(tile[tx][ty + i]);
        }
        return;
    }

    // ROI align, gather-reordered: block = c (256 blocks). Thread t -> n = t&127,
    // p parity p0 = t>>7; loops p = p0, p0+2, ... (t<128: 5 iters, t>=128: 4).
    // All of a block's 4608 corner loads live in the <=10 planes of its c
    // (disjoint across blocks); boxes/idx loads coalesce over consecutive n.
    {
        int c = blk - 704;
        int n = t & 127;
        int p0 = t >> 7;

        int lvl = level_idx[n];
        int b = batch_idx[n];
        const float sizes[5]  = {128.f, 64.f, 32.f, 16.f, 8.f};
        const float invstr[5] = {1.f/8.f, 1.f/16.f, 1.f/32.f, 1.f/64.f, 1.f/128.f};
        float scale = invstr[lvl];
        float hv = sizes[lvl];

        float x1 = boxes[n*4+0] * scale, y1 = boxes[n*4+1] * scale;
        float x2 = boxes[n*4+2] * scale, y2 = boxes[n*4+3] * scale;
        float rw = fmaxf(x2 - x1, 1.f), rh = fmaxf(y2 - y1, 1.f);
        int hi = (int)(hv - 1.f);

        const float* base = fm + (((size_t)lvl * 2 + b) * 256 + c) * (128 * 128);

        for (int p = p0; p < 9; p += 2) {
            int i = p / 3, j = p % 3;
            float x = x1 + (((float)j + 0.5f) / 3.f) * rw;
            float y = y1 + (((float)i + 0.5f) / 3.f) * rh;

            bool valid = (y > -1.f) && (y < hv) && (x > -1.f) && (x < hv);
            float yc = fminf(fmaxf(y, 0.f), hv - 1.f);
            float xc = fminf(fmaxf(x, 0.f), hv - 1.f);
            int y0 = (int)floorf(yc), x0 = (int)floorf(xc);
            int y1i = min(y0 + 1, hi), x1i = min(x0 + 1, hi);
            float ly = yc - (float)y0, lx = xc - (float)x0;

            float v00 = base[y0 * 128 + x0];
            float v01 = base[y0 * 128 + x1i];
            float v10 = base[y1i * 128 + x0];
            float v11 = base[y1i * 128 + x1i];
            float v = (1.f - ly) * (1.f - lx) * v00 + (1.f - ly) * lx * v01 +
                      ly * (1.f - lx) * v10 + ly * lx * v11;
            roiT[((size_t)n * 9 + p) * 256 + c] = valid ? v : 0.f;
        }
    }
}

// ---------------- conv3x3 + GroupNorm + ReLU + spatial-mean ----------------
// Block = (n-pair, e-quarter): 256 blocks x 512 threads.
// thread: e_loc = t&63, ch = t>>6 (8 c-slices of 32 channels, c in pairs).
// Sample pair packed in v2f lanes (.x = n0, .y = n1) -> v_pk_fma_f32; roi values
// wave-uniform -> s_load_dwordx2 over adjacent c. GN group = e/32: 32-lane halves.
__global__ __launch_bounds__(512, 2) void conv_gn_pool(
    const float* __restrict__ roiT,
    const unsigned short* __restrict__ w8, const unsigned short* __restrict__ w9,
    const float* __restrict__ gn_scale, const float* __restrict__ gn_bias,
    float* __restrict__ pooled) {
    __shared__ float redA[4 * 64 * 9];
    __shared__ float redB[4 * 64 * 9];

    int np = blockIdx.x >> 2;             // 0..63 sample pair
    int eq = blockIdx.x & 3;
    int n0 = np * 2, n1 = n0 + 1;
    int t = threadIdx.x;
    int e_loc = t & 63;
    int ch = __builtin_amdgcn_readfirstlane(t >> 6);   // wave-uniform 0..7
    int e = eq * 64 + e_loc;

    const float* r0 = roiT + (size_t)n0 * 2304;   // [p][c]
    const float* r1 = roiT + (size_t)n1 * 2304;

    v2f acc[9];
#pragma unroll
    for (int p = 0; p < 9; ++p) acc[p] = (v2f)(0.f);

    int c0 = ch * 32;
#pragma unroll 2
    for (int c = c0; c < c0 + 32; c += 2) {
        // wave-uniform float2 roi loads (adjacent c, 8B-aligned) -> s_load_dwordx2
        v2f q0[9], q1[9];                 // q0: sample0 (c, c+1), q1: sample1
#pragma unroll
        for (int jj = 0; jj < 9; ++jj) {
            q0[jj] = *(const v2f*)(r0 + jj * 256 + c);
            q1[jj] = *(const v2f*)(r1 + jj * 256 + c);
        }
        // sample-packed uniform pairs per c
        v2f rc0[9], rc1[9];
#pragma unroll
        for (int jj = 0; jj < 9; ++jj) {
            rc0[jj].x = q0[jj].x; rc0[jj].y = q1[jj].x;   // channel c
            rc1[jj].x = q0[jj].y; rc1[jj].y = q1[jj].y;   // channel c+1
        }
#pragma unroll
        for (int cc = 0; cc < 2; ++cc) {
            const v2f* r = cc ? rc1 : rc0;
            int cw = c + cc;
            uint4 wa4 = ((const uint4*)w8)[(size_t)cw * 256 + e];
            float wv[9];
            wv[0] = bf_lo(wa4.x); wv[1] = bf_hi(wa4.x);
            wv[2] = bf_lo(wa4.y); wv[3] = bf_hi(wa4.y);
            wv[4] = bf_lo(wa4.z); wv[5] = bf_hi(wa4.z);
            wv[6] = bf_lo(wa4.w); wv[7] = bf_hi(wa4.w);
            wv[8] = bf_lo((unsigned)w9[(size_t)cw * 256 + e]);
#pragma unroll
            for (int ky = 0; ky < 3; ++ky) {
#pragma unroll
                for (int kx = 0; kx < 3; ++kx) {
                    v2f w2;
                    w2.x = wv[ky * 3 + kx]; w2.y = wv[ky * 3 + kx];
#pragma unroll
                    for (int oy = 0; oy < 3; ++oy) {
                        int iy = oy + ky - 1;
                        if (iy < 0 || iy > 2) continue;
#pragma unroll
                        for (int ox = 0; ox < 3; ++ox) {
                            int ix = ox + kx - 1;
                            if (ix < 0 || ix > 2) continue;
                            int o = oy * 3 + ox, in = iy * 3 + ix;
                            acc[o] = w2 * r[in] + acc[o];   // -> v_pk_fma_f32
                        }
                    }
                }
            }
        }
    }

    float acc0[9], acc1[9];
#pragma unroll
    for (int p = 0; p < 9; ++p) { acc0[p] = acc[p].x; acc1[p] = acc[p].y; }

    // tree-reduce 8 c-slices into ch==0 (sample0) / ch==1 (sample1)
    if (ch >= 4) {
#pragma unroll
        for (int p = 0; p < 9; ++p) {
            redA[((ch - 4) * 64 + e_loc) * 9 + p] = acc0[p];
            redB[((ch - 4) * 64 + e_loc) * 9 + p] = acc1[p];
        }
    }
    __syncthreads();
    if (ch < 4) {
#pragma unroll
        for (int p = 0; p < 9; ++p) {
            acc0[p] += redA[(ch * 64 + e_loc) * 9 + p];
            acc1[p] += redB[(ch * 64 + e_loc) * 9 + p];
        }
    }
    __syncthreads();
    if (ch >= 2 && ch < 4) {
#pragma unroll
        for (int p = 0; p < 9; ++p) {
            redA[((ch - 2) * 64 + e_loc) * 9 + p] = acc0[p];
            redB[((ch - 2) * 64 + e_loc) * 9 + p] = acc1[p];
        }
    }
    __syncthreads();
    if (ch < 2) {
#pragma unroll
        for (int p = 0; p < 9; ++p) {
            acc0[p] += redA[(ch * 64 + e_loc) * 9 + p];
            acc1[p] += redB[(ch * 64 + e_loc) * 9 + p];
        }
    }
    __syncthreads();
    if (ch == 1) {
#pragma unroll
        for (int p = 0; p < 9; ++p) redA[e_loc * 9 + p] = acc0[p];
    }
    if (ch == 0) {
#pragma unroll
        for (int p = 0; p < 9; ++p) redB[e_loc * 9 + p] = acc1[p];
    }
    __syncthreads();

    if (ch < 2) {
        float accf[9];
        int n_out;
        if (ch == 0) {
            n_out = n0;
#pragma unroll
            for (int p = 0; p < 9; ++p) accf[p] = acc0[p] + redA[e_loc * 9 + p];
        } else {
            n_out = n1;
#pragma unroll
            for (int p = 0; p < 9; ++p) accf[p] = acc1[p] + redB[e_loc * 9 + p];
        }

        float s = 0.f, sq = 0.f;
#pragma unroll
        for (int p = 0; p < 9; ++p) { s += accf[p]; sq += accf[p] * accf[p]; }
#pragma unroll
        for (int m = 16; m >= 1; m >>= 1) {
            s  += __shfl_xor(s, m, 64);
            sq += __shfl_xor(sq, m, 64);
        }
        float mean = s * (1.f / 288.f);
        float var = sq * (1.f / 288.f) - mean * mean;
        float rinv = rsqrtf(var + 1e-5f);
        float gs = gn_scale[e], gb = gn_bias[e];
        float ps = 0.f;
#pragma unroll
        for (int p = 0; p < 9; ++p) {
            float v = (accf[p] - mean) * rinv * gs + gb;
            ps += fmaxf(v, 0.f);
        }
        pooled[(size_t)n_out * 256 + e] = ps * (1.f / 9.f);
    }
}

// ---------------- head GEMM + spat + sym_emb + fuse matvec (k-split x2) ----------------
// block = n (128 blocks x 512 threads). t = kh*256 + e. Weights are transposed,
// k-paired bf16: one uint per lane = taps (2k, 2k+1) for its e — coalesced 4B/lane.
__global__ __launch_bounds__(512) void head_fuse(
    const float* __restrict__ pooled, const float* __restrict__ boxes,
    const unsigned short* __restrict__ head_wTb, const float* __restrict__ head_b,
    const float* __restrict__ spat_w, const float* __restrict__ spat_b,
    const float* __restrict__ sym_emb,
    const unsigned short* __restrict__ fuse_wTb, const float* __restrict__ fuse_b,
    const int* __restrict__ sym_ids, float* __restrict__ out) {
    __shared__ float pl[256];
    __shared__ float part[512];
    __shared__ float fin[256];
    int n = blockIdx.x;
    int t = threadIdx.x;
    int e = t & 255;
    int kh = t >> 8;                      // 0/1
    int sid = sym_ids[n];

    if (t < 256) pl[t] = pooled[(size_t)n * 256 + t];
    __syncthreads();

    {
        float acc = 0.f;
        const unsigned* w = (const unsigned*)head_wTb + (size_t)(kh * 64) * 256 + e;
        const float* p = pl + kh * 128;
#pragma unroll 8
        for (int kp = 0; kp < 64; ++kp) {
            unsigned u = w[kp * 256];
            acc = fmaf(p[2 * kp],     bf_lo(u), acc);
            acc = fmaf(p[2 * kp + 1], bf_hi(u), acc);
        }
        part[t] = acc;
    }
    __syncthreads();
    if (t < 256) {
        float ho = fmaxf(part[t] + part[t + 256] + head_b[t], 0.f);
        float4 sw = ((const float4*)spat_w)[t];
        float b0 = boxes[n*4+0], b1 = boxes[n*4+1], b2 = boxes[n*4+2], b3 = boxes[n*4+3];
        float sp = fmaxf(spat_b[t] + b0*sw.x + b1*sw.y + b2*sw.z + b3*sw.w, 0.f);
        fin[t] = ho + sp + sym_emb[sid * 256 + t];
    }
    __syncthreads();
    {
        float o = 0.f;
        const unsigned* w = (const unsigned*)fuse_wTb + (size_t)sid * 32768
                            + (size_t)(kh * 64) * 256 + e;
        const float* p = fin + kh * 128;
#pragma unroll 8
        for (int kp = 0; kp < 64; ++kp) {
            unsigned u = w[kp * 256];
            o = fmaf(p[2 * kp],     bf_lo(u), o);
            o = fmaf(p[2 * kp + 1], bf_hi(u), o);
        }
        part[t] = o;
    }
    __syncthreads();
    if (t < 256)
        out[(size_t)n * 256 + t] = fmaxf(part[t] + part[t + 256] + fuse_b[sid * 256 + t], 0.f);
}

extern "C" void kernel_launch(void* const* d_in, const int* in_sizes, int n_in,
                              void* d_out, int out_size, void* d_ws, size_t ws_size,
                              hipStream_t stream) {
    const float* fm      = (const float*)d_in[0];
    const float* boxes   = (const float*)d_in[1];
    const float* conv_w  = (const float*)d_in[2];
    const float* gn_s    = (const float*)d_in[3];
    const float* gn_b    = (const float*)d_in[4];
    const float* head_w  = (const float*)d_in[5];
    const float* head_b  = (const float*)d_in[6];
    const float* spat_w  = (const float*)d_in[7];
    const float* spat_b  = (const float*)d_in[8];
    const float* sym_emb = (const float*)d_in[9];
    const float* fuse_w  = (const float*)d_in[10];
    const float* fuse_b  = (const float*)d_in[11];
    const int* batch_idx = (const int*)d_in[12];
    const int* level_idx = (const int*)d_in[13];
    const int* sym_ids   = (const int*)d_in[14];
    float* outp = (float*)d_out;

    char* ws = (char*)d_ws;
    unsigned short* w8       = (unsigned short*)ws;             // [256c][256e][8] bf16: 1,048,576 B
    unsigned short* w9       = (unsigned short*)(ws + 1048576); // [256c][256e] bf16  :   131,072 B
    unsigned short* head_wTb = (unsigned short*)(ws + 1179648); // [128kp][256e][2]   :   131,072 B
    unsigned short* fuse_wTb = (unsigned short*)(ws + 1310720); // [6][128kp][256e][2]:   786,432 B
    float* roiT    = (float*)(ws + 2097152);                    // [128][9][256]      : 1,179,648 B
    float* pooled  = (float*)(ws + 3276800);                    // [128][256]         :   131,072 B

    prep_k<<<960, 256, 0, stream>>>(conv_w, head_w, fuse_w, fm, boxes,
                                    batch_idx, level_idx,
                                    w8, w9, head_wTb, fuse_wTb, roiT);
    conv_gn_pool<<<256, 512, 0, stream>>>(roiT, w8, w9, gn_s, gn_b, pooled);
    head_fuse<<<128, 512, 0, stream>>>(pooled, boxes, head_wTb, head_b, spat_w, spat_b,
                                       sym_emb, fuse_wTb, fuse_b, sym_ids, outp);
}